// Round 5
// baseline (107.595 us; speedup 1.0000x reference)
//
#include <hip/hip_runtime.h>

#define NN 512
#define DD 9
#define LL 32
#define NT 32   // 16x16 tiles per dimension

typedef _Float16 f16x8 __attribute__((ext_vector_type(8)));
typedef float    f32x4 __attribute__((ext_vector_type(4)));
typedef unsigned long long u64;

__device__ __forceinline__ u64 umin64(u64 a, u64 b) { return a < b ? a : b; }

// One block per batch element, 1024 threads = 16 waves.
// MFMA (16x16x32 f16, K=16 used) computes cross(i,j) = -2 x_i . y_j via hi/lo
// f16 split (exact products, rep error 2^-21). d = x2[i] + y2[j] + cross, then
// fmax 0 — same association as the reference. Argmin via u64 keys
// (dbits<<32)|idx: unsigned min == lexicographic (d, first-index). Per-wave
// partials merge through private LDS slots (no atomics, deterministic).
__global__ __launch_bounds__(1024, 4)
void loss_kernel(const float* __restrict__ kine_input,
                 const float* __restrict__ class_input,
                 const float* __restrict__ kine_pred,
                 const float* __restrict__ class_pred,
                 const float* __restrict__ mu,
                 const float* __restrict__ log_var,
                 float* __restrict__ out)
{
    const int b    = (int)blockIdx.x;
    const int t    = (int)threadIdx.x;
    const int lane = t & 63;
    const int wave = t >> 6;

    __shared__ f16x8 sA[NT * 64];        // A' fragments (input side), 32 KB
    __shared__ f16x8 sB[NT * 64];        // B' fragments (pred side),  32 KB
    __shared__ float sx2[NN], sy2[NN];   // squared norms, 4 KB
    __shared__ u64   row_part[2][NN];    // per-th row-min partials, 8 KB
    __shared__ u64   col_part[8][NN];    // per-tb col-min partials, 32 KB
    __shared__ float red[16];
    __shared__ float s_kl;
    __shared__ int   hist_in[DD], hist_pr[DD];

    if (t < DD) { hist_in[t] = 0; hist_pr[t] = 0; }

    // ---- stage fragments: slot s = rep*1024+t; side|ti|lane decode ----
    // lane ln: row/col = ti*16 + (ln&15), kg = ln>>4. k = kg*8+e, used k<16:
    // c = k&3, p = k>>2. A: p<2 -> whi (w=-2x), else wlo. B: e<4 -> yhi else ylo.
    #pragma unroll
    for (int rep = 0; rep < 4; ++rep) {
        const int s    = rep * 1024 + t;
        const int side = s >> 11;
        const int ti   = (s >> 6) & 31;
        const int ln   = s & 63;
        const int row  = ti * 16 + (ln & 15);
        const int kg   = ln >> 4;
        const float* P = side ? kine_pred : kine_input;
        float4 pt = *reinterpret_cast<const float4*>(P + ((size_t)b * NN + row) * 4);
        float n = pt.x*pt.x + pt.y*pt.y + pt.z*pt.z + pt.w*pt.w;
        if (kg == 0) { (side ? sy2 : sx2)[row] = n; }
        float w[4];
        if (side == 0) { w[0] = -2.f*pt.x; w[1] = -2.f*pt.y; w[2] = -2.f*pt.z; w[3] = -2.f*pt.w; }
        else           { w[0] =      pt.x; w[1] =      pt.y; w[2] =      pt.z; w[3] =      pt.w; }
        _Float16 hi[4], lo[4];
        #pragma unroll
        for (int c = 0; c < 4; ++c) { hi[c] = (_Float16)w[c]; lo[c] = (_Float16)(w[c] - (float)hi[c]); }
        f16x8 hv;
        #pragma unroll
        for (int e = 0; e < 8; ++e) {
            _Float16 v = (_Float16)0.f;
            if (kg < 2) {
                const int c = e & 3;
                if (side == 0) v = (kg == 0) ? hi[c] : lo[c];       // p = kg*2+(e>>2): p<2 <=> kg==0
                else           v = (e < 4) ? hi[c] : lo[c];         // p&1 == e>>2
            }
            hv[e] = v;
        }
        (side ? sB : sA)[ti * 64 + ln] = hv;
    }
    __syncthreads();

    // ---- main pass: wave = (tb = wave>>1: 4 row-tiles) x (th = wave&1: 16 col-tiles) ----
    const int tb = wave >> 1, th = wave & 1;
    const int ti0 = tb * 4, tj0 = th * 16;

    f16x8 afr[4];
    int   rowb[4];
    float x2r[16];
    #pragma unroll
    for (int q = 0; q < 4; ++q) {
        afr[q]  = sA[(ti0 + q) * 64 + lane];
        rowb[q] = (ti0 + q) * 16 + ((lane >> 4) << 2);
        #pragma unroll
        for (int r = 0; r < 4; ++r) x2r[q * 4 + r] = sx2[rowb[q] + r];
    }

    u64 rp[16];
    #pragma unroll
    for (int i = 0; i < 16; ++i) rp[i] = ~0ull;

    const f32x4 zero = {0.f, 0.f, 0.f, 0.f};

    #pragma unroll 2
    for (int jj = 0; jj < 16; ++jj) {
        const int tj = tj0 + jj;
        f16x8 bfr = sB[tj * 64 + lane];
        const unsigned colg = (unsigned)(tj * 16 + (lane & 15));
        const float y2c = sy2[colg];
        u64 cp = ~0ull;
        #pragma unroll
        for (int q = 0; q < 4; ++q) {
            f32x4 d4 = __builtin_amdgcn_mfma_f32_16x16x32_f16(afr[q], bfr, zero, 0, 0, 0);
            #pragma unroll
            for (int r = 0; r < 4; ++r) {
                float d = fmaxf(x2r[q * 4 + r] + y2c + d4[r], 0.f);   // matches ref order + clamp
                const u64 hib = ((u64)__float_as_uint(d)) << 32;
                rp[q * 4 + r] = umin64(rp[q * 4 + r], hib | (u64)colg);
                cp            = umin64(cp,            hib | (u64)(unsigned)(rowb[q] + r));
            }
        }
        cp = umin64(cp, (u64)__shfl_xor((unsigned long long)cp, 16, 64));
        cp = umin64(cp, (u64)__shfl_xor((unsigned long long)cp, 32, 64));
        if (lane < 16) col_part[tb][colg] = cp;
    }

    #pragma unroll
    for (int q = 0; q < 4; ++q) {
        #pragma unroll
        for (int r = 0; r < 4; ++r) {
            u64 v = rp[q * 4 + r];
            v = umin64(v, (u64)__shfl_xor((unsigned long long)v, 1, 64));
            v = umin64(v, (u64)__shfl_xor((unsigned long long)v, 2, 64));
            v = umin64(v, (u64)__shfl_xor((unsigned long long)v, 4, 64));
            v = umin64(v, (u64)__shfl_xor((unsigned long long)v, 8, 64));
            if ((lane & 15) == 0) row_part[th][rowb[q] + r] = v;
        }
    }

    // ---- histograms (labels independent of argmins) + KL ----
    {
        const float* cls = (t < NN) ? class_input : class_pred;
        const int r = t & (NN - 1);
        const float* rowp = cls + ((size_t)b * NN + r) * DD;
        float mx = rowp[0]; int lab = 0;
        #pragma unroll
        for (int d2 = 1; d2 < DD; ++d2) { float v = rowp[d2]; if (v > mx) { mx = v; lab = d2; } }  // argmax(exp)==argmax
        atomicAdd((t < NN) ? &hist_in[lab] : &hist_pr[lab], 1);
    }
    if (t < 64) {
        float v = 0.f;
        if (t < LL) {
            float m_ = mu[(size_t)b * LL + t];
            float lv = log_var[(size_t)b * LL + t];
            v = 1.f + lv - m_ * m_ - expf(lv);
        }
        #pragma unroll
        for (int off = 32; off > 0; off >>= 1) v += __shfl_down(v, off, 64);
        if (t == 0) s_kl = -0.5f * v;
    }
    __syncthreads();

    // ---- final merge + epilogue: thread t -> (pass p, row lr) ----
    float part;
    {
        const int p  = t >> 9;
        const int lr = t & (NN - 1);
        u64 e;
        if (p == 0) {
            e = umin64(row_part[0][lr], row_part[1][lr]);
        } else {
            e = col_part[0][lr];
            #pragma unroll
            for (int k = 1; k < 8; ++k) e = umin64(e, col_part[k][lr]);
        }
        const int idx = (int)(e & 511u);
        const float dmin = __uint_as_float((unsigned)(e >> 32));
        const float* own = (p ? class_pred  : class_input) + ((size_t)b * NN + lr) * DD;
        const float* oth = (p ? class_input : class_pred)  + ((size_t)b * NN + idx) * DD;
        float dot = 0.f;
        #pragma unroll
        for (int d2 = 0; d2 < DD; ++d2) dot += own[d2] * oth[d2];
        part = dmin - dot;   // chamfer + (-1)*class dot (W=1)
    }
    #pragma unroll
    for (int off = 32; off > 0; off >>= 1) part += __shfl_down(part, off, 64);
    if (lane == 0) red[wave] = part;
    __syncthreads();

    if (t == 0) {
        float sum = 0.f;
        #pragma unroll
        for (int w2 = 0; w2 < 16; ++w2) sum += red[w2];
        float cnum = 0.f;
        #pragma unroll
        for (int c = 0; c < DD; ++c) {
            float diff = fabsf((float)(hist_pr[c] - hist_in[c]));
            float wgt = (c == 0) ? 2.0f : ((c == DD - 1) ? 100.0f : 1.0f);
            cnum += wgt * diff;
        }
        out[b] = 0.99f * (sum + 0.001f * cnum) + 0.01f * s_kl;
    }
}

extern "C" void kernel_launch(void* const* d_in, const int* in_sizes, int n_in,
                              void* d_out, int out_size, void* d_ws, size_t ws_size,
                              hipStream_t stream) {
    const float* kine_input  = (const float*)d_in[0];
    const float* class_input = (const float*)d_in[1];
    const float* kine_pred   = (const float*)d_in[2];
    const float* class_pred  = (const float*)d_in[3];
    const float* mu          = (const float*)d_in[4];
    const float* log_var     = (const float*)d_in[5];
    float* out = (float*)d_out;

    loss_kernel<<<256, 1024, 0, stream>>>(kine_input, class_input, kine_pred,
                                          class_pred, mu, log_var, out);
}

// Round 6
// 33.398 us; speedup vs baseline: 3.2216x; 3.2216x over previous
//
#include <hip/hip_runtime.h>

#define NN 512
#define DD 9
#define LL 32
#define NT 32   // 16x16 tiles per dimension

typedef _Float16 f16x8 __attribute__((ext_vector_type(8)));
typedef float    f32x4 __attribute__((ext_vector_type(4)));
typedef unsigned long long u64;

__device__ __forceinline__ u64 umin64(u64 a, u64 b) { return a < b ? a : b; }

// One block per batch element, 1024 threads = 16 waves.
// MFMA (16x16x32 f16, K=16 used) computes cross(i,j) = -2 x_i . y_j via hi/lo
// f16 split (exact products). d = x2[i] + y2[j] + cross, fmax 0 — same
// association as the reference. Argmin via u64 keys (dbits<<32)|idx: unsigned
// min == lexicographic (d, first-index). Wave w owns row-tiles {2w, 2w+1} and
// scans ALL 32 col-tiles: row minima have a unique writer (direct store);
// col minima merge via LDS atomicMin u64 (commutative -> deterministic).
// Register budget ~55 VGPRs: no spills (R5 failure mode).
__global__ __launch_bounds__(1024)
void loss_kernel(const float* __restrict__ kine_input,
                 const float* __restrict__ class_input,
                 const float* __restrict__ kine_pred,
                 const float* __restrict__ class_pred,
                 const float* __restrict__ mu,
                 const float* __restrict__ log_var,
                 float* __restrict__ out)
{
    const int b    = (int)blockIdx.x;
    const int t    = (int)threadIdx.x;
    const int lane = t & 63;
    const int wave = t >> 6;

    __shared__ f16x8 sA[NT * 64];        // A' fragments (input side), 32 KB
    __shared__ f16x8 sB[NT * 64];        // B' fragments (pred side),  32 KB
    __shared__ float sx2[NN], sy2[NN];   // squared norms, 4 KB
    __shared__ u64   row_arr[NN];        // final row minima, 4 KB
    __shared__ u64   col_arr[NN];        // atomicMin-merged col minima, 4 KB
    __shared__ float red[16];
    __shared__ float s_kl;
    __shared__ int   hist_in[DD], hist_pr[DD];

    if (t < NN) col_arr[t] = ~0ull;
    if (t < DD) { hist_in[t] = 0; hist_pr[t] = 0; }

    // ---- stage fragments: slot s = rep*1024+t -> side|ti|lane ----
    // lane ln: row/col = ti*16 + (ln&15), kg = ln>>4. k = kg*8+e, used k<16:
    // A: kg==0 -> hi(-2x), kg==1 -> lo. B: e<4 -> hi(y), e>=4 -> lo.
    #pragma unroll
    for (int rep = 0; rep < 4; ++rep) {
        const int s    = rep * 1024 + t;
        const int side = s >> 11;
        const int ti   = (s >> 6) & 31;
        const int ln   = s & 63;
        const int row  = ti * 16 + (ln & 15);
        const int kg   = ln >> 4;
        const float* P = side ? kine_pred : kine_input;
        float4 pt = *reinterpret_cast<const float4*>(P + ((size_t)b * NN + row) * 4);
        float n = pt.x*pt.x + pt.y*pt.y + pt.z*pt.z + pt.w*pt.w;
        if (kg == 0) { (side ? sy2 : sx2)[row] = n; }
        float w[4];
        if (side == 0) { w[0] = -2.f*pt.x; w[1] = -2.f*pt.y; w[2] = -2.f*pt.z; w[3] = -2.f*pt.w; }
        else           { w[0] =      pt.x; w[1] =      pt.y; w[2] =      pt.z; w[3] =      pt.w; }
        _Float16 hi[4], lo[4];
        #pragma unroll
        for (int c = 0; c < 4; ++c) { hi[c] = (_Float16)w[c]; lo[c] = (_Float16)(w[c] - (float)hi[c]); }
        f16x8 hv;
        #pragma unroll
        for (int e = 0; e < 8; ++e) {
            _Float16 v = (_Float16)0.f;
            if (kg < 2) {
                const int c = e & 3;
                if (side == 0) v = (kg == 0) ? hi[c] : lo[c];
                else           v = (e < 4) ? hi[c] : lo[c];
            }
            hv[e] = v;
        }
        (side ? sB : sA)[ti * 64 + ln] = hv;
    }
    __syncthreads();

    // ---- main pass: wave owns row-tiles {2w, 2w+1}, scans all 32 col-tiles ----
    const int ti0 = wave * 2;

    f16x8 afr[2];
    int   rowb[2];
    float x2r[8];
    #pragma unroll
    for (int q = 0; q < 2; ++q) {
        afr[q]  = sA[(ti0 + q) * 64 + lane];
        rowb[q] = (ti0 + q) * 16 + ((lane >> 4) << 2);
        #pragma unroll
        for (int r = 0; r < 4; ++r) x2r[q * 4 + r] = sx2[rowb[q] + r];
    }

    u64 rp[8];
    #pragma unroll
    for (int i = 0; i < 8; ++i) rp[i] = ~0ull;

    const f32x4 zero = {0.f, 0.f, 0.f, 0.f};

    #pragma unroll 2
    for (int jj = 0; jj < NT; ++jj) {
        f16x8 bfr = sB[jj * 64 + lane];
        const unsigned colg = (unsigned)(jj * 16 + (lane & 15));
        const float y2c = sy2[colg];
        u64 cp = ~0ull;
        #pragma unroll
        for (int q = 0; q < 2; ++q) {
            f32x4 d4 = __builtin_amdgcn_mfma_f32_16x16x32_f16(afr[q], bfr, zero, 0, 0, 0);
            #pragma unroll
            for (int r = 0; r < 4; ++r) {
                float d = fmaxf(x2r[q * 4 + r] + y2c + d4[r], 0.f);   // ref order + clamp
                const u64 hib = ((u64)__float_as_uint(d)) << 32;
                rp[q * 4 + r] = umin64(rp[q * 4 + r], hib | (u64)colg);
                cp            = umin64(cp,            hib | (u64)(unsigned)(rowb[q] + r));
            }
        }
        // reduce col partial over the wave's 32 rows (4 lane-groups)
        cp = umin64(cp, (u64)__shfl_xor((unsigned long long)cp, 16, 64));
        cp = umin64(cp, (u64)__shfl_xor((unsigned long long)cp, 32, 64));
        if (lane < 16) atomicMin(&col_arr[colg], cp);   // 16 consecutive u64: conflict-free
    }

    // ---- row minima: unique writer per row, direct store ----
    #pragma unroll
    for (int q = 0; q < 2; ++q) {
        #pragma unroll
        for (int r = 0; r < 4; ++r) {
            u64 v = rp[q * 4 + r];
            v = umin64(v, (u64)__shfl_xor((unsigned long long)v, 1, 64));
            v = umin64(v, (u64)__shfl_xor((unsigned long long)v, 2, 64));
            v = umin64(v, (u64)__shfl_xor((unsigned long long)v, 4, 64));
            v = umin64(v, (u64)__shfl_xor((unsigned long long)v, 8, 64));
            if ((lane & 15) == 0) row_arr[rowb[q] + r] = v;
        }
    }

    // ---- histograms (labels independent of argmins) + KL ----
    {
        const float* cls = (t < NN) ? class_input : class_pred;
        const int r = t & (NN - 1);
        const float* rowp = cls + ((size_t)b * NN + r) * DD;
        float mx = rowp[0]; int lab = 0;
        #pragma unroll
        for (int d2 = 1; d2 < DD; ++d2) { float v = rowp[d2]; if (v > mx) { mx = v; lab = d2; } }  // argmax(exp)==argmax
        atomicAdd((t < NN) ? &hist_in[lab] : &hist_pr[lab], 1);
    }
    if (t < 64) {
        float v = 0.f;
        if (t < LL) {
            float m_ = mu[(size_t)b * LL + t];
            float lv = log_var[(size_t)b * LL + t];
            v = 1.f + lv - m_ * m_ - expf(lv);
        }
        #pragma unroll
        for (int off = 32; off > 0; off >>= 1) v += __shfl_down(v, off, 64);
        if (t == 0) s_kl = -0.5f * v;
    }
    __syncthreads();

    // ---- epilogue: thread t -> (pass p, row lr); unpack, class dot ----
    float part;
    {
        const int p  = t >> 9;
        const int lr = t & (NN - 1);
        const u64 e = p ? col_arr[lr] : row_arr[lr];
        const int idx = (int)(e & 511u);
        const float dmin = __uint_as_float((unsigned)(e >> 32));
        const float* own = (p ? class_pred  : class_input) + ((size_t)b * NN + lr) * DD;
        const float* oth = (p ? class_input : class_pred)  + ((size_t)b * NN + idx) * DD;
        float dot = 0.f;
        #pragma unroll
        for (int d2 = 0; d2 < DD; ++d2) dot += own[d2] * oth[d2];
        part = dmin - dot;   // chamfer + (-1)*class dot (W=1)
    }
    #pragma unroll
    for (int off = 32; off > 0; off >>= 1) part += __shfl_down(part, off, 64);
    if (lane == 0) red[wave] = part;
    __syncthreads();

    if (t == 0) {
        float sum = 0.f;
        #pragma unroll
        for (int w2 = 0; w2 < 16; ++w2) sum += red[w2];
        float cnum = 0.f;
        #pragma unroll
        for (int c = 0; c < DD; ++c) {
            float diff = fabsf((float)(hist_pr[c] - hist_in[c]));
            float wgt = (c == 0) ? 2.0f : ((c == DD - 1) ? 100.0f : 1.0f);
            cnum += wgt * diff;
        }
        out[b] = 0.99f * (sum + 0.001f * cnum) + 0.01f * s_kl;
    }
}

extern "C" void kernel_launch(void* const* d_in, const int* in_sizes, int n_in,
                              void* d_out, int out_size, void* d_ws, size_t ws_size,
                              hipStream_t stream) {
    const float* kine_input  = (const float*)d_in[0];
    const float* class_input = (const float*)d_in[1];
    const float* kine_pred   = (const float*)d_in[2];
    const float* class_pred  = (const float*)d_in[3];
    const float* mu          = (const float*)d_in[4];
    const float* log_var     = (const float*)d_in[5];
    float* out = (float*)d_out;

    loss_kernel<<<256, 1024, 0, stream>>>(kine_input, class_input, kine_pred,
                                          class_pred, mu, log_var, out);
}